// Round 14
// baseline (339.635 us; speedup 1.0000x reference)
//
#include <hip/hip_runtime.h>
#include <math.h>

#define NN 50000
#define NE 800000
#define NEG_SLOPE 0.2f
#define LN_EPS 1e-5f

typedef unsigned short ushort_t;
typedef unsigned int uint_t;
typedef __attribute__((ext_vector_type(8))) short bf16x8;
typedef __attribute__((ext_vector_type(4))) float f32x4;

__device__ __forceinline__ float bf2f(ushort_t u) {
    return __uint_as_float(((uint_t)u) << 16);
}
__device__ __forceinline__ ushort_t f2bf(float f) {
    uint_t b = __float_as_uint(f);
    uint_t r = (b + 0x7fffu + ((b >> 16) & 1u)) >> 16;
    return (ushort_t)r;
}
__device__ __forceinline__ float ldx(const void* p, size_t i, int isbf) {
    return isbf ? bf2f(((const ushort_t*)p)[i]) : ((const float*)p)[i];
}
__device__ __forceinline__ int clampN(int v) {
    return v < 0 ? 0 : (v >= NN ? NN - 1 : v);
}
__device__ __forceinline__ int ld_src(const int* ei, int e, int f64) {
    return clampN(f64 ? ei[2 * e] : ei[e]);
}
__device__ __forceinline__ int ld_dst(const int* ei, int e, int f64) {
    return clampN(f64 ? ei[2 * NE + 2 * e] : ei[NE + e]);
}
__device__ __forceinline__ int sniff_isbf(const void* hptr) {
    const ushort_t* hu = (const ushort_t*)hptr;
    int bf = 1;
    for (int i = 0; i < 512; i += 2) {
        uint_t ex = (hu[i] >> 7) & 0xFFu;
        if (ex > 0x8Cu) bf = 0;  // |v| >= ~1e4 -> not bf16 data
    }
    return bf;
}
__device__ __forceinline__ int sniff_f64(const int* ei) {
    return (ei[1] == 0 && ei[3] == 0 && ei[5] == 0 && ei[7] == 0) ? 1 : 0;
}

// Setup: flags + zero deg + M (block0) + u vectors + w2 + optional h->bf16.
// u[l][j][d] (j<4: src head j, j>=4: dst head j-4) = sum_c W[l,h*64+c,d]*att[l,h,c]
// w2[l][c][h*64+kk] = 0.25 * W[l][h*64+c][kk]   (weights for the post-GEMM,
// mean-over-heads folded in)
__global__ __launch_bounds__(256) void setup(
    const void* __restrict__ lin_W, const void* __restrict__ lin_edge_W,
    const void* __restrict__ att_src, const void* __restrict__ att_dst,
    const void* __restrict__ att_edge, const void* __restrict__ h_in,
    const int* __restrict__ ei, float* __restrict__ Mbuf,
    ushort_t* __restrict__ ubuf, ushort_t* __restrict__ w2,
    ushort_t* __restrict__ hbf, int* __restrict__ deg, int* __restrict__ flags) {
    int tid = threadIdx.x, lane = tid & 63;
    int nthreads = gridDim.x * 256;
    int gtid = blockIdx.x * 256 + tid;
    __shared__ int s_isbf;
    if (tid == 0) s_isbf = sniff_isbf(h_in);
    __syncthreads();
    int isbf = s_isbf;
    if (gtid == 0) {
        flags[0] = sniff_f64(ei);
        flags[1] = isbf;
    }
    for (int i = gtid; i < NN; i += nthreads) deg[i] = 0;
    if (blockIdx.x == 0) {
        for (int rep = 0; rep < 2; ++rep) {
            int idx = rep * 256 + tid;  // l=idx>>8, h=(idx>>6)&3, c=idx&63
            int l = idx >> 8, hc = idx & 255;
            float ae = ldx(att_edge, l * 256 + hc, isbf);
            size_t b3 = ((size_t)l * 256 + hc) * 3;
            float q0 = ae * ldx(lin_edge_W, b3 + 0, isbf);
            float q1 = ae * ldx(lin_edge_W, b3 + 1, isbf);
            float q2 = ae * ldx(lin_edge_W, b3 + 2, isbf);
            for (int off = 32; off > 0; off >>= 1) {
                q0 += __shfl_down(q0, off);
                q1 += __shfl_down(q1, off);
                q2 += __shfl_down(q2, off);
            }
            if (lane == 0) {
                int h = (idx >> 6) & 3;
                Mbuf[(l * 4 + h) * 3 + 0] = q0;
                Mbuf[(l * 4 + h) * 3 + 1] = q1;
                Mbuf[(l * 4 + h) * 3 + 2] = q2;
            }
        }
    }
    // u vectors: 2*8*64 = 1024 elems
    for (int idx = gtid; idx < 1024; idx += nthreads) {
        int l = idx >> 9, j = (idx >> 6) & 7, d = idx & 63;
        int h = j & 3;
        const void* att = (j < 4) ? att_src : att_dst;
        float v = 0.f;
        for (int c = 0; c < 64; ++c) {
            v += ldx(lin_W, ((size_t)l * 256 + h * 64 + c) * 64 + d, isbf) *
                 ldx(att, l * 256 + h * 64 + c, isbf);
        }
        ubuf[idx] = f2bf(v);
    }
    // w2: 2*64*256 = 32768 elems
    for (int idx = gtid; idx < 32768; idx += nthreads) {
        int l = idx >> 14;
        int rem = idx & 16383;
        int c = rem >> 8, k = rem & 255;
        int h = k >> 6, kk = k & 63;
        float v = 0.25f * ldx(lin_W, ((size_t)l * 256 + h * 64 + c) * 64 + kk, isbf);
        w2[idx] = f2bf(v);
    }
    if (!isbf) {
        for (int i = gtid; i < NN * 64; i += nthreads)
            hbf[i] = f2bf(((const float*)h_in)[i]);
    }
}

// ---------------- CSR build (r13-proven, unchanged) ----------------

__global__ void csr_hist_pos(const int* __restrict__ ei, int* __restrict__ deg,
                             int* __restrict__ pos, const int* __restrict__ flags) {
    int e = blockIdx.x * 256 + threadIdx.x;
    if (e >= NE) return;
    pos[e] = atomicAdd(&deg[ld_dst(ei, e, flags[0])], 1);
}

__global__ __launch_bounds__(1024) void csr_scan(const int* __restrict__ deg,
                                                 int* __restrict__ rowptr) {
    __shared__ int sh[1024];
    __shared__ int prefix_sh;
    int tid = threadIdx.x;
    int i = blockIdx.x * 1024 + tid;
    int pre = 0;
    for (int k = tid; k < blockIdx.x * 1024; k += 1024) pre += deg[k];
    sh[tid] = pre;
    __syncthreads();
    for (int off = 512; off > 0; off >>= 1) {
        if (tid < off) sh[tid] += sh[tid + off];
        __syncthreads();
    }
    if (tid == 0) prefix_sh = sh[0];
    __syncthreads();
    int prefix = prefix_sh;
    __syncthreads();
    int v = (i < NN) ? deg[i] : 0;
    sh[tid] = v;
    __syncthreads();
    for (int off = 1; off < 1024; off <<= 1) {
        int t = (tid >= off) ? sh[tid - off] : 0;
        __syncthreads();
        sh[tid] += t;
        __syncthreads();
    }
    if (i < NN) rowptr[i] = prefix + sh[tid] - v;
    if (i == 0) rowptr[NN] = NE;
}

__global__ void csr_fill(const int* __restrict__ ei, const void* __restrict__ edge_attr,
                         const int* __restrict__ rowptr, const int* __restrict__ pos,
                         float4* __restrict__ edata, const int* __restrict__ flags) {
    int e = blockIdx.x * 256 + threadIdx.x;
    if (e >= NE) return;
    int f64 = flags[0], isbf = flags[1];
    int s = ld_src(ei, e, f64), d = ld_dst(ei, e, f64);
    float4 ed;
    ed.x = ldx(edge_attr, (size_t)e * 3 + 0, isbf);
    ed.y = ldx(edge_attr, (size_t)e * 3 + 1, isbf);
    ed.z = ldx(edge_attr, (size_t)e * 3 + 2, isbf);
    ed.w = __int_as_float(s);
    edata[rowptr[d] + pos[e]] = ed;
}

// ---------------- per-layer kernels ----------------

// A: a_src/a_dst[n][4] = z[n] . u[l][j]  (thread = (node, j), j=0..7)
__global__ __launch_bounds__(256) void node_attn(
    const void* __restrict__ h_in, const ushort_t* __restrict__ hbf,
    const ushort_t* __restrict__ zbuf, const ushort_t* __restrict__ ubuf,
    float* __restrict__ a_src, float* __restrict__ a_dst,
    const int* __restrict__ flags, int layer) {
    int idx = blockIdx.x * 256 + threadIdx.x;
    int n = idx >> 3, j = idx & 7;
    if (n >= NN) return;
    int isbf = flags[1];
    const ushort_t* zsrc = (layer == 0) ? (isbf ? (const ushort_t*)h_in : hbf) : zbuf;
    const uint_t* zr = (const uint_t*)(zsrc + (size_t)n * 64);
    const uint_t* ur = (const uint_t*)(ubuf + ((size_t)layer * 8 + j) * 64);
    float acc = 0.f;
#pragma unroll
    for (int i = 0; i < 32; ++i) {
        uint_t za = zr[i], ua = ur[i];
        acc += __uint_as_float(za << 16) * __uint_as_float(ua << 16) +
               __uint_as_float(za & 0xffff0000u) * __uint_as_float(ua & 0xffff0000u);
    }
    if (j < 4) a_src[n * 4 + j] = acc;
    else       a_dst[n * 4 + (j - 4)] = acc;
}

// B: one wave per node. Gathers z rows (128 B/edge, 4x less than old xb),
// accumulates 4 head-accumulators; denominators via butterfly at staging.
// Output t[n][h*64+c] = acc_h/den_h (bf16).
__global__ __launch_bounds__(256) void node_aggregate(
    const int* __restrict__ rowptr, const float4* __restrict__ edata,
    const float* __restrict__ a_src, const float* __restrict__ a_dst,
    const void* __restrict__ h_in, const ushort_t* __restrict__ hbf,
    const ushort_t* __restrict__ zbuf, const float* __restrict__ Mbuf,
    ushort_t* __restrict__ t, const int* __restrict__ flags, int layer) {
    __shared__ float4 wsh[4][64];
    __shared__ int ssh[4][64];
    int isbf = flags[1];
    int wv = threadIdx.x >> 6;
    int lane = threadIdx.x & 63;
    int n = blockIdx.x * 4 + wv;
    const ushort_t* zsrc = (layer == 0) ? (isbf ? (const ushort_t*)h_in : hbf) : zbuf;
    float M[12];
#pragma unroll
    for (int i = 0; i < 12; ++i) M[i] = Mbuf[layer * 12 + i];
    float4 ad = *(const float4*)(a_dst + (size_t)n * 4);
    int start = rowptr[n], end = rowptr[n + 1];
    float acc0 = 0.f, acc1 = 0.f, acc2 = 0.f, acc3 = 0.f;
    float den0 = 0.f, den1 = 0.f, den2 = 0.f, den3 = 0.f;
    for (int cb = start; cb < end; cb += 64) {
        int m = end - cb;
        if (m > 64) m = 64;
        float4 ex = make_float4(0.f, 0.f, 0.f, 0.f);
        int s = 0;
        if (lane < m) {
            float4 ed = edata[cb + lane];
            s = __float_as_int(ed.w);
            float4 as4 = *(const float4*)(a_src + (size_t)s * 4);
            float t0 = as4.x + ad.x + ed.x * M[0] + ed.y * M[1] + ed.z * M[2];
            float t1 = as4.y + ad.y + ed.x * M[3] + ed.y * M[4] + ed.z * M[5];
            float t2 = as4.z + ad.z + ed.x * M[6] + ed.y * M[7] + ed.z * M[8];
            float t3 = as4.w + ad.w + ed.x * M[9] + ed.y * M[10] + ed.z * M[11];
            t0 = t0 > 0.f ? t0 : NEG_SLOPE * t0;
            t1 = t1 > 0.f ? t1 : NEG_SLOPE * t1;
            t2 = t2 > 0.f ? t2 : NEG_SLOPE * t2;
            t3 = t3 > 0.f ? t3 : NEG_SLOPE * t3;
            ex.x = __expf(fminf(t0, 80.f));
            ex.y = __expf(fminf(t1, 80.f));
            ex.z = __expf(fminf(t2, 80.f));
            ex.w = __expf(fminf(t3, 80.f));
        }
        wsh[wv][lane] = ex;
        ssh[wv][lane] = s;
        // denominators: butterfly over the chunk (pads are zero)
        float d0 = ex.x, d1 = ex.y, d2 = ex.z, d3 = ex.w;
        for (int off = 1; off < 64; off <<= 1) {
            d0 += __shfl_xor(d0, off);
            d1 += __shfl_xor(d1, off);
            d2 += __shfl_xor(d2, off);
            d3 += __shfl_xor(d3, off);
        }
        den0 += d0; den1 += d1; den2 += d2; den3 += d3;
        for (int j = 0; j < m; j += 4) {
            int s0 = ssh[wv][j],     s1 = ssh[wv][j + 1];
            int s2 = ssh[wv][j + 2], s3 = ssh[wv][j + 3];
            float4 w0 = wsh[wv][j];
            float4 w1 = wsh[wv][j + 1];
            float4 w2 = wsh[wv][j + 2];
            float4 w3 = wsh[wv][j + 3];
            float z0 = bf2f(zsrc[(size_t)s0 * 64 + lane]);
            float z1 = bf2f(zsrc[(size_t)s1 * 64 + lane]);
            float z2 = bf2f(zsrc[(size_t)s2 * 64 + lane]);
            float z3 = bf2f(zsrc[(size_t)s3 * 64 + lane]);
            acc0 += w0.x * z0 + w1.x * z1 + w2.x * z2 + w3.x * z3;
            acc1 += w0.y * z0 + w1.y * z1 + w2.y * z2 + w3.y * z3;
            acc2 += w0.z * z0 + w1.z * z1 + w2.z * z2 + w3.z * z3;
            acc3 += w0.w * z0 + w1.w * z1 + w2.w * z2 + w3.w * z3;
        }
    }
    size_t tb = (size_t)n * 256 + lane;
    t[tb]       = f2bf(acc0 / (den0 + 1e-16f));
    t[tb + 64]  = f2bf(acc1 / (den1 + 1e-16f));
    t[tb + 128] = f2bf(acc2 / (den2 + 1e-16f));
    t[tb + 192] = f2bf(acc3 / (den3 + 1e-16f));
}

// C: out = 0.25*Wcat.t + bias -> LN -> SiLU. MFMA (r7-verified operand
// pattern: A=w2 row frag, B=t row frag; D col=lane&15 -> node, row=q*4+r ->
// out channel). w2 fragments register-resident. LDS stage + fused LN.
__global__ __launch_bounds__(256) void node_post(
    const ushort_t* __restrict__ t, const ushort_t* __restrict__ w2,
    const void* __restrict__ bias, const void* __restrict__ gamma,
    const void* __restrict__ beta, ushort_t* __restrict__ zout,
    void* __restrict__ outp, const int* __restrict__ flags, int layer, int last) {
    __shared__ __align__(16) float st_all[4][16][68];  // 17408 B
    int isbf = flags[1];
    int tid = threadIdx.x, wv = tid >> 6, lane = tid & 63;
    int q = lane >> 4, mi = lane & 15;
    const ushort_t* w2l = w2 + (size_t)layer * 64 * 256;
    bf16x8 af[4][8];
#pragma unroll
    for (int ct = 0; ct < 4; ++ct) {
        const ushort_t* wrow = w2l + (size_t)(ct * 16 + mi) * 256;
#pragma unroll
        for (int kt = 0; kt < 8; ++kt)
            af[ct][kt] = *(const bf16x8*)(wrow + kt * 32 + q * 8);
    }
    float bz = ldx(bias, layer * 64 + lane, isbf);
    float gm = ldx(gamma, layer * 64 + lane, isbf);
    float bt = ldx(beta, layer * 64 + lane, isbf);
    int gwave = blockIdx.x * 4 + wv, nwaves = gridDim.x * 4;
    for (int tile = gwave; tile < NN / 16; tile += nwaves) {
        int mbase = tile * 16, mynode = mbase + mi;
        const ushort_t* trow = t + (size_t)mynode * 256;
        bf16x8 bf[8];
#pragma unroll
        for (int kt = 0; kt < 8; ++kt)
            bf[kt] = *(const bf16x8*)(trow + kt * 32 + q * 8);
#pragma unroll
        for (int ct = 0; ct < 4; ++ct) {
            f32x4 acc = {0.f, 0.f, 0.f, 0.f};
#pragma unroll
            for (int kt = 0; kt < 8; ++kt)
                acc = __builtin_amdgcn_mfma_f32_16x16x32_bf16(af[ct][kt], bf[kt], acc, 0, 0, 0);
#pragma unroll
            for (int r = 0; r < 4; ++r)
                st_all[wv][mi][ct * 16 + q * 4 + r] = acc[r];
        }
        // LN + SiLU per node (lane = channel)
        for (int nn = 0; nn < 16; ++nn) {
            float v = st_all[wv][nn][lane] + bz;
            float sum = v;
            for (int off = 1; off < 64; off <<= 1) sum += __shfl_xor(sum, off);
            float mu = sum * (1.f / 64.f);
            float d = v - mu;
            float vv = d * d;
            for (int off = 1; off < 64; off <<= 1) vv += __shfl_xor(vv, off);
            float var = vv * (1.f / 64.f);
            float ln = d * rsqrtf(var + LN_EPS) * gm + bt;
            float sl = ln / (1.f + __expf(-ln));
            size_t idx = (size_t)(mbase + nn) * 64 + lane;
            if (last) {
                if (isbf) ((ushort_t*)outp)[idx] = f2bf(sl);
                else      ((float*)outp)[idx] = sl;
            } else {
                zout[idx] = f2bf(sl);
            }
        }
    }
}

extern "C" void kernel_launch(void* const* d_in, const int* in_sizes, int n_in,
                              void* d_out, int out_size, void* d_ws, size_t ws_size,
                              hipStream_t stream) {
    int off = (in_sizes[0] == 1) ? 1 : 0;
    const void* h_in  = d_in[off + 0];
    const int*  ei    = (const int*)d_in[off + 1];
    const void* eattr = d_in[off + 2];
    const void* linW  = d_in[off + 3];
    const void* linEW = d_in[off + 4];
    const void* attS  = d_in[off + 5];
    const void* attD  = d_in[off + 6];
    const void* attE  = d_in[off + 7];
    const void* bias  = d_in[off + 8];
    const void* gamma = d_in[off + 9];
    const void* beta  = d_in[off + 10];

    // bump allocator, 256 B aligned (~56 MB)
    char* w = (char*)d_ws;
    size_t o = 0;
    auto alloc = [&](size_t bytes) {
        void* q = w + o;
        o += (bytes + 255) & ~(size_t)255;
        return q;
    };
    int*    flags  = (int*)alloc(8);
    float*  Mbuf   = (float*)alloc(24 * 4);
    ushort_t* ubuf = (ushort_t*)alloc((size_t)2 * 8 * 64 * 2);
    ushort_t* w2   = (ushort_t*)alloc((size_t)2 * 64 * 256 * 2);
    float*  a_src  = (float*)alloc((size_t)NN * 4 * 4);
    float*  a_dst  = (float*)alloc((size_t)NN * 4 * 4);
    int*    rowptr = (int*)alloc((size_t)(NN + 1) * 4);
    int*    deg    = (int*)alloc((size_t)NN * 4);
    int*    pos    = (int*)alloc((size_t)NE * 4);
    ushort_t* zbuf = (ushort_t*)alloc((size_t)NN * 64 * 2);
    ushort_t* hbf  = (ushort_t*)alloc((size_t)NN * 64 * 2);
    ushort_t* tbuf = (ushort_t*)alloc((size_t)NN * 256 * 2);
    float4* edata  = (float4*)alloc((size_t)NE * 16);

    int nb = (NN + 1023) / 1024;  // 49
    setup<<<256, 256, 0, stream>>>(linW, linEW, attS, attD, attE, h_in, ei,
                                   Mbuf, ubuf, w2, hbf, deg, flags);
    csr_hist_pos<<<(NE + 255) / 256, 256, 0, stream>>>(ei, deg, pos, flags);
    csr_scan<<<nb, 1024, 0, stream>>>(deg, rowptr);
    csr_fill<<<(NE + 255) / 256, 256, 0, stream>>>(ei, eattr, rowptr, pos, edata, flags);

    for (int l = 0; l < 2; ++l) {
        node_attn<<<(NN * 8 + 255) / 256, 256, 0, stream>>>(h_in, hbf, zbuf, ubuf,
                                                            a_src, a_dst, flags, l);
        node_aggregate<<<NN / 4, 256, 0, stream>>>(rowptr, edata, a_src, a_dst,
                                                   h_in, hbf, zbuf, Mbuf, tbuf,
                                                   flags, l);
        node_post<<<512, 256, 0, stream>>>(tbuf, w2, bias, gamma, beta, zbuf,
                                           d_out, flags, l, l == 1);
    }
}